// Round 1
// baseline (382.328 us; speedup 1.0000x reference)
//
#include <hip/hip_runtime.h>

typedef unsigned short u16;
typedef __attribute__((ext_vector_type(8))) short short8;
typedef __attribute__((ext_vector_type(4))) float f32x4;
typedef __attribute__((ext_vector_type(8))) unsigned short ushort8;

__device__ __forceinline__ u16 f2bf(float f) {
  unsigned u = __float_as_uint(f);
  u += 0x7FFFu + ((u >> 16) & 1u);
  return (u16)(u >> 16);
}
__device__ __forceinline__ float bf2f(u16 h) {
  return __uint_as_float(((unsigned)h) << 16);
}

#define GLD(gsrc, ldst)                                                        \
  __builtin_amdgcn_global_load_lds(                                            \
      (const __attribute__((address_space(1))) void*)(gsrc),                   \
      (__attribute__((address_space(3))) void*)(ldst), 16, 0, 0)

// ---------------- prep kernels ----------------

// lam, lam^128, gamma.  cst layout: [0..511] lam_r, [512..] lam_i,
// [1024..] lamL_r, [1536..] lamL_i, [2048..] gamma
__global__ void k_const(const float* __restrict__ nu_log,
                        const float* __restrict__ theta_log,
                        const float* __restrict__ gamma_log,
                        float* __restrict__ cst) {
  int h = threadIdx.x;  // 512 threads
  float mag = expf(-expf(nu_log[h]));
  float th  = expf(theta_log[h]);
  float lr = mag * cosf(th), li = mag * sinf(th);
  cst[h] = lr;
  cst[512 + h] = li;
  float pr = lr, pi = li;
#pragma unroll
  for (int i = 0; i < 7; ++i) {  // lam^128 via 7 squarings
    float nr = pr * pr - pi * pi;
    pi = 2.f * pr * pi;
    pr = nr;
  }
  cst[1024 + h] = pr;
  cst[1536 + h] = pi;
  cst[2048 + h] = expf(gamma_log[h]);
}

// dst[c*DL + r] = bf16(sgn * src[r*C + c]) ; tiled 32x32, 256 threads
__global__ __launch_bounds__(256) void transpose_cvt(
    const float* __restrict__ src, u16* __restrict__ dst, int R, int C, int DL,
    float sgn) {
  __shared__ float t[32][33];
  int bc = blockIdx.x << 5, brr = blockIdx.y << 5;
  int tx = threadIdx.x & 31, ty = threadIdx.x >> 5;  // ty 0..7
#pragma unroll
  for (int i = 0; i < 32; i += 8)
    t[ty + i][tx] = src[(size_t)(brr + ty + i) * C + bc + tx];
  __syncthreads();
#pragma unroll
  for (int i = 0; i < 32; i += 8)
    dst[(size_t)(bc + ty + i) * DL + brr + tx] = f2bf(sgn * t[tx][ty + i]);
}

// f32 -> bf16, 8 elems/thread
__global__ __launch_bounds__(256) void cast_bf(const float* __restrict__ in,
                                               u16* __restrict__ out) {
  int g = blockIdx.x * 256 + threadIdx.x;
  const float4* p = (const float4*)in + (size_t)g * 2;
  float4 a = p[0], b = p[1];
  ushort8 o;
  o[0] = f2bf(a.x); o[1] = f2bf(a.y); o[2] = f2bf(a.z); o[3] = f2bf(a.w);
  o[4] = f2bf(b.x); o[5] = f2bf(b.y); o[6] = f2bf(b.z); o[7] = f2bf(b.w);
  ((ushort8*)out)[g] = o;
}

// ---------------- GEMM (m97 structure) ----------------
// C[M,N] = A[M,K] @ Bt[N,K]^T ; A,Bt bf16 row-major; 128x128 tile, BK=32,
// 4 waves, each wave 64x64 via 4x4 frags of mfma_f32_16x16x32_bf16.
// EPI 0: u = gamma[h]*(acc + (n<512?br:bi)[h]) -> bf16      (e0=gamma,e1=br,e2=bi)
// EPI 1: y = acc + cr[n] - ci[n] -> f32                      (e0=cr,e1=ci)
// EPI 2: h1 = acc + b1[n] -> bf16                            (e0=b1)
// EPI 3: out = acc + b2[n] -> f32                            (e0=b2)
template <int EPI>
__global__ __launch_bounds__(256, 2) void gemm_bt(
    const u16* __restrict__ A, const u16* __restrict__ Bt,
    void* __restrict__ Cv, int M, int N, int K, const float* __restrict__ e0,
    const float* __restrict__ e1, const float* __restrict__ e2) {
  __shared__ u16 As[128 * 32];
  __shared__ u16 Bs[128 * 32];
  const int tid = threadIdx.x;
  const int wave = tid >> 6;
  const int lane = tid & 63;
  const int m0 = blockIdx.x * 128;
  const int n0 = blockIdx.y * 128;

  // staging: issue i covers rows i*64 + wave*16 + lane/4, 16B per lane
  const int srow = (wave << 4) + (lane >> 2);
  const int scol = (lane & 3) * 8;
  const u16* gA = A + (size_t)(m0 + srow) * K + scol;
  const u16* gB = Bt + (size_t)(n0 + srow) * K + scol;
  u16* lA = (u16*)As + (wave << 9);
  u16* lB = (u16*)Bs + (wave << 9);
  const size_t rstep = (size_t)64 * K;

  const int wm = (wave >> 1) << 6;
  const int wn = (wave & 1) << 6;
  const int fr = lane & 15;
  const int fk = (lane >> 4) << 3;

  f32x4 acc[4][4] = {};

  for (int kt = 0; kt < K; kt += 32) {
    GLD(gA, lA);
    GLD(gA + rstep, lA + 2048);
    GLD(gB, lB);
    GLD(gB + rstep, lB + 2048);
    gA += 32;
    gB += 32;
    __syncthreads();  // drains vmcnt (global_load_lds) + barrier
    short8 a[4], b[4];
#pragma unroll
    for (int i = 0; i < 4; ++i) {
      a[i] = *(const short8*)(&As[(wm + (i << 4) + fr) * 32 + fk]);
      b[i] = *(const short8*)(&Bs[(wn + (i << 4) + fr) * 32 + fk]);
    }
#pragma unroll
    for (int i = 0; i < 4; ++i)
#pragma unroll
      for (int j = 0; j < 4; ++j)
        acc[i][j] =
            __builtin_amdgcn_mfma_f32_16x16x32_bf16(a[i], b[j], acc[i][j], 0, 0, 0);
    __syncthreads();
  }

  // epilogue: C/D map col=lane&15, row=(lane>>4)*4+q  [m89-verified]
  const int r0 = m0 + wm + ((lane >> 4) << 2);
  const int c0 = n0 + wn + (lane & 15);
#pragma unroll
  for (int i = 0; i < 4; ++i) {
#pragma unroll
    for (int j = 0; j < 4; ++j) {
#pragma unroll
      for (int q = 0; q < 4; ++q) {
        int m = r0 + (i << 4) + q;
        int n = c0 + (j << 4);
        float v = acc[i][j][q];
        if constexpr (EPI == 0) {
          int h = n & 511;
          float bias = (n < 512) ? e1[h] : e2[h];
          ((u16*)Cv)[(size_t)m * N + n] = f2bf(e0[h] * (v + bias));
        } else if constexpr (EPI == 1) {
          ((float*)Cv)[(size_t)m * N + n] = v + e0[n] - e1[n];
        } else if constexpr (EPI == 2) {
          ((u16*)Cv)[(size_t)m * N + n] = f2bf(v + e0[n]);
        } else {
          ((float*)Cv)[(size_t)m * N + n] = v + e0[n];
        }
      }
    }
  }
}

// ---------------- scan (chunked: 16 chunks x 128 steps) ----------------
// u layout: [m=b*2048+t][1024] bf16, cols 0..511 = ur, 512..1023 = ui

__global__ __launch_bounds__(256) void scan_fin(const u16* __restrict__ u,
                                                const float* __restrict__ cst,
                                                float2* __restrict__ fin) {
  int g = blockIdx.x * 256 + threadIdx.x;  // 131072
  int h = g & 511, b = (g >> 9) & 15, c = g >> 13;
  float lr = cst[h], li = cst[512 + h];
  const u16* pr = u + ((size_t)(b * 2048 + c * 128)) * 1024 + h;
  float fr = 0.f, fi = 0.f;
#pragma unroll 4
  for (int j = 0; j < 128; ++j) {
    float ur = bf2f(pr[0]), ui = bf2f(pr[512]);
    float nr = fmaf(lr, fr, fmaf(-li, fi, ur));
    float ni = fmaf(lr, fi, fmaf(li, fr, ui));
    fr = nr;
    fi = ni;
    pr += 1024;
  }
  fin[(size_t)(c * 16 + b) * 512 + h] = make_float2(fr, fi);
}

__global__ __launch_bounds__(256) void scan_carry(const float2* __restrict__ fin,
                                                  const float* __restrict__ cst,
                                                  float2* __restrict__ carry) {
  int g = blockIdx.x * 256 + threadIdx.x;  // 8192
  int h = g & 511, b = g >> 9;
  float lr = cst[1024 + h], li = cst[1536 + h];  // lam^128
  float sr = 0.f, si = 0.f;
#pragma unroll
  for (int c = 0; c < 16; ++c) {
    size_t idx = (size_t)(c * 16 + b) * 512 + h;
    carry[idx] = make_float2(sr, si);
    float2 f = fin[idx];
    float nr = fmaf(lr, sr, fmaf(-li, si, f.x));
    float ni = fmaf(lr, si, fmaf(li, sr, f.y));
    sr = nr;
    si = ni;
  }
}

__global__ __launch_bounds__(256) void scan_out(const u16* __restrict__ u,
                                                const float* __restrict__ cst,
                                                const float2* __restrict__ carry,
                                                u16* __restrict__ hcat) {
  int g = blockIdx.x * 256 + threadIdx.x;
  int h = g & 511, b = (g >> 9) & 15, c = g >> 13;
  float lr = cst[h], li = cst[512 + h];
  size_t mb = ((size_t)(b * 2048 + c * 128)) * 1024;
  const u16* pr = u + mb + h;
  u16* qr = hcat + mb + h;
  float2 s0 = carry[(size_t)(c * 16 + b) * 512 + h];
  float sr = s0.x, si = s0.y;
#pragma unroll 4
  for (int j = 0; j < 128; ++j) {
    float ur = bf2f(pr[0]), ui = bf2f(pr[512]);
    float nr = fmaf(lr, sr, fmaf(-li, si, ur));
    float ni = fmaf(lr, si, fmaf(li, sr, ui));
    sr = nr;
    si = ni;
    qr[0] = f2bf(sr);
    qr[512] = f2bf(si);
    pr += 1024;
    qr += 1024;
  }
}

// ---------------- LayerNorm ----------------
__global__ __launch_bounds__(256) void ln_kernel(const float* __restrict__ y,
                                                 const float* __restrict__ sc,
                                                 const float* __restrict__ bs,
                                                 u16* __restrict__ out) {
  int row = blockIdx.x * 4 + (threadIdx.x >> 6);
  int lane = threadIdx.x & 63;
  const float4* yr = (const float4*)(y + (size_t)row * 512);
  float4 v0 = yr[lane * 2], v1 = yr[lane * 2 + 1];
  float s = v0.x + v0.y + v0.z + v0.w + v1.x + v1.y + v1.z + v1.w;
  float q = v0.x * v0.x + v0.y * v0.y + v0.z * v0.z + v0.w * v0.w +
            v1.x * v1.x + v1.y * v1.y + v1.z * v1.z + v1.w * v1.w;
#pragma unroll
  for (int m = 32; m >= 1; m >>= 1) {
    s += __shfl_xor(s, m, 64);
    q += __shfl_xor(q, m, 64);
  }
  float mean = s * (1.f / 512.f);
  float var = q * (1.f / 512.f) - mean * mean;
  float rstd = rsqrtf(var + 1e-6f);
  int jb = lane * 8;
  const float4* scp = (const float4*)(sc + jb);
  const float4* bsp = (const float4*)(bs + jb);
  float4 s0 = scp[0], s1 = scp[1], b0 = bsp[0], b1 = bsp[1];
  ushort8 o;
  o[0] = f2bf((v0.x - mean) * rstd * s0.x + b0.x);
  o[1] = f2bf((v0.y - mean) * rstd * s0.y + b0.y);
  o[2] = f2bf((v0.z - mean) * rstd * s0.z + b0.z);
  o[3] = f2bf((v0.w - mean) * rstd * s0.w + b0.w);
  o[4] = f2bf((v1.x - mean) * rstd * s1.x + b1.x);
  o[5] = f2bf((v1.y - mean) * rstd * s1.y + b1.y);
  o[6] = f2bf((v1.z - mean) * rstd * s1.z + b1.z);
  o[7] = f2bf((v1.w - mean) * rstd * s1.w + b1.w);
  ((ushort8*)(out + (size_t)row * 512))[lane] = o;
}

// ---------------- launch ----------------
extern "C" void kernel_launch(void* const* d_in, const int* in_sizes, int n_in,
                              void* d_out, int out_size, void* d_ws,
                              size_t ws_size, hipStream_t stream) {
  const float* x   = (const float*)d_in[0];
  const float* nu  = (const float*)d_in[1];
  const float* th  = (const float*)d_in[2];
  const float* gl  = (const float*)d_in[3];
  const float* Br  = (const float*)d_in[4];
  const float* br  = (const float*)d_in[5];
  const float* Bi  = (const float*)d_in[6];
  const float* bi  = (const float*)d_in[7];
  const float* Cr  = (const float*)d_in[8];
  const float* cr  = (const float*)d_in[9];
  const float* Ci  = (const float*)d_in[10];
  const float* ci  = (const float*)d_in[11];
  const float* lns = (const float*)d_in[12];
  const float* lnb = (const float*)d_in[13];
  const float* W1  = (const float*)d_in[14];
  const float* b1  = (const float*)d_in[15];
  const float* W2  = (const float*)d_in[16];
  const float* b2  = (const float*)d_in[17];

  char* ws = (char*)d_ws;
  size_t off = 0;
  auto alloc = [&](size_t bytes) {
    char* p = ws + off;
    off += (bytes + 255) & ~(size_t)255;
    return p;
  };
  float* cst  = (float*)alloc(2560 * 4);
  u16* BcT    = (u16*)alloc((size_t)1024 * 512 * 2);   // [n<512:Br | n>=512:Bi][k]
  u16* WcT    = (u16*)alloc((size_t)512 * 1024 * 2);   // [n][k<512:Cr | k>=512:-Ci]
  u16* W1T    = (u16*)alloc((size_t)2048 * 512 * 2);
  u16* W2T    = (u16*)alloc((size_t)512 * 2048 * 2);
  float2* fin = (float2*)alloc((size_t)16 * 16 * 512 * 8);
  float2* car = (float2*)alloc((size_t)16 * 16 * 512 * 8);
  u16* xb     = (u16*)alloc((size_t)32768 * 512 * 2);   // also ybn after LN
  u16* big1   = (u16*)alloc((size_t)32768 * 1024 * 2);  // u ; then y(f32) ; then h1 lo
  u16* big2   = (u16*)alloc((size_t)32768 * 1024 * 2);  // hcat ; then h1 hi
  (void)in_sizes; (void)n_in; (void)out_size; (void)ws_size;

  // prep
  k_const<<<dim3(1), dim3(512), 0, stream>>>(nu, th, gl, cst);
  transpose_cvt<<<dim3(16, 16), dim3(256), 0, stream>>>(Br, BcT, 512, 512, 512, 1.f);
  transpose_cvt<<<dim3(16, 16), dim3(256), 0, stream>>>(Bi, BcT + 512 * 512, 512, 512, 512, 1.f);
  transpose_cvt<<<dim3(16, 16), dim3(256), 0, stream>>>(Cr, WcT, 512, 512, 1024, 1.f);
  transpose_cvt<<<dim3(16, 16), dim3(256), 0, stream>>>(Ci, WcT + 512, 512, 512, 1024, -1.f);
  transpose_cvt<<<dim3(64, 16), dim3(256), 0, stream>>>(W1, W1T, 512, 2048, 512, 1.f);
  transpose_cvt<<<dim3(16, 64), dim3(256), 0, stream>>>(W2, W2T, 2048, 512, 2048, 1.f);
  cast_bf<<<dim3(8192), dim3(256), 0, stream>>>(x, xb);

  // G1: u = gamma*(x@[Br|Bi] + [br|bi])  -> big1 (bf16 [32768][1024])
  gemm_bt<0><<<dim3(256, 8), dim3(256), 0, stream>>>(
      xb, BcT, (void*)big1, 32768, 1024, 512, cst + 2048, br, bi);
  // scan
  scan_fin<<<dim3(512), dim3(256), 0, stream>>>(big1, cst, fin);
  scan_carry<<<dim3(32), dim3(256), 0, stream>>>(fin, cst, car);
  scan_out<<<dim3(512), dim3(256), 0, stream>>>(big1, cst, car, big2);
  // G2: y = [hr|hi] @ [Cr;-Ci] + (cr-ci) -> f32 into big1 slot
  gemm_bt<1><<<dim3(256, 4), dim3(256), 0, stream>>>(
      big2, WcT, (void*)big1, 32768, 512, 1024, cr, ci, nullptr);
  // LN -> bf16 into xb slot
  ln_kernel<<<dim3(8192), dim3(256), 0, stream>>>((const float*)big1, lns, lnb, xb);
  // G3: h1 = ybn@W1 + b1 -> bf16 into big1+big2 (contiguous 128MiB)
  gemm_bt<2><<<dim3(256, 16), dim3(256), 0, stream>>>(
      xb, W1T, (void*)big1, 32768, 2048, 512, b1, nullptr, nullptr);
  // G4: out = h1@W2 + b2 -> f32 d_out
  gemm_bt<3><<<dim3(256, 4), dim3(256), 0, stream>>>(
      big1, W2T, d_out, 32768, 512, 2048, b2, nullptr, nullptr);
}

// Round 2
// 355.711 us; speedup vs baseline: 1.0748x; 1.0748x over previous
//
#include <hip/hip_runtime.h>

typedef unsigned short u16;
typedef __attribute__((ext_vector_type(8))) short short8;
typedef __attribute__((ext_vector_type(4))) float f32x4;
typedef __attribute__((ext_vector_type(8))) unsigned short ushort8;

__device__ __forceinline__ u16 f2bf(float f) {
  unsigned u = __float_as_uint(f);
  u += 0x7FFFu + ((u >> 16) & 1u);
  return (u16)(u >> 16);
}
__device__ __forceinline__ float bf2f(u16 h) {
  return __uint_as_float(((unsigned)h) << 16);
}

#define GLD(gsrc, ldst)                                                        \
  __builtin_amdgcn_global_load_lds(                                            \
      (const __attribute__((address_space(1))) void*)(gsrc),                   \
      (__attribute__((address_space(3))) void*)(ldst), 16, 0, 0)

// ---------------- prep kernels ----------------

__global__ void k_const(const float* __restrict__ nu_log,
                        const float* __restrict__ theta_log,
                        const float* __restrict__ gamma_log,
                        float* __restrict__ cst) {
  int h = threadIdx.x;  // 512 threads
  float mag = expf(-expf(nu_log[h]));
  float th  = expf(theta_log[h]);
  float lr = mag * cosf(th), li = mag * sinf(th);
  cst[h] = lr;
  cst[512 + h] = li;
  float pr = lr, pi = li;
#pragma unroll
  for (int i = 0; i < 7; ++i) {  // lam^128 via 7 squarings
    float nr = pr * pr - pi * pi;
    pi = 2.f * pr * pi;
    pr = nr;
  }
  cst[1024 + h] = pr;
  cst[1536 + h] = pi;
  cst[2048 + h] = expf(gamma_log[h]);
}

// dst[c*DL + r] = bf16(sgn * src[r*C + c]) ; tiled 32x32, 256 threads
__global__ __launch_bounds__(256) void transpose_cvt(
    const float* __restrict__ src, u16* __restrict__ dst, int R, int C, int DL,
    float sgn) {
  __shared__ float t[32][33];
  int bc = blockIdx.x << 5, brr = blockIdx.y << 5;
  int tx = threadIdx.x & 31, ty = threadIdx.x >> 5;  // ty 0..7
#pragma unroll
  for (int i = 0; i < 32; i += 8)
    t[ty + i][tx] = src[(size_t)(brr + ty + i) * C + bc + tx];
  __syncthreads();
#pragma unroll
  for (int i = 0; i < 32; i += 8)
    dst[(size_t)(bc + ty + i) * DL + brr + tx] = f2bf(sgn * t[tx][ty + i]);
}

// f32 -> bf16, 8 elems/thread
__global__ __launch_bounds__(256) void cast_bf(const float* __restrict__ in,
                                               u16* __restrict__ out) {
  int g = blockIdx.x * 256 + threadIdx.x;
  const float4* p = (const float4*)in + (size_t)g * 2;
  float4 a = p[0], b = p[1];
  ushort8 o;
  o[0] = f2bf(a.x); o[1] = f2bf(a.y); o[2] = f2bf(a.z); o[3] = f2bf(a.w);
  o[4] = f2bf(b.x); o[5] = f2bf(b.y); o[6] = f2bf(b.z); o[7] = f2bf(b.w);
  ((ushort8*)out)[g] = o;
}

// ---------------- GEMM: 256x256 tile, BK=64, 8-phase counted-vmcnt ----------
// C[M,N] = A[M,K] @ Bt[N,K]^T ; A,Bt bf16 row-major.
// 8 waves (2M x 4N), per-wave 128x64 out, mfma_f32_16x16x32_bf16.
// LDS 128 KiB: sA/sB [2 bufs][256 rows][64 cols] bf16, XOR-swizzled
// (colbyte ^= (row&7)<<4) with linear global_load_lds dest + pre-swizzled
// global source (rule #21: both-sides-or-neither).
// Phases per K-tile t (buf c=t&1): P0 {read A[M0](8)+B[N0](4); stage A0(t+1)},
// P1 {read B[N1](4); stage A1(t+1)}, P2 {read A[M1](8); stage B0(t+2)},
// P3 {stage B1(t+2); vmcnt(4)}.  vmcnt never 0 in steady state.
template <int EPI>
__global__ __launch_bounds__(512, 2) void gemm8p(
    const u16* __restrict__ A, const u16* __restrict__ Bt, void* __restrict__ Cv,
    int M, int N, int K, const float* __restrict__ e0,
    const float* __restrict__ e1, const float* __restrict__ e2) {
  __shared__ u16 sA[2][256 * 64];
  __shared__ u16 sB[2][256 * 64];
  const int tid = threadIdx.x;
  const int w = tid >> 6, l = tid & 63;

  // XCD-aware bijective swizzle (nwg % 8 == 0 for all our shapes)
  const int nbx = M >> 8;
  const int nwg = gridDim.x;
  int wg = blockIdx.x;
  wg = (wg & 7) * (nwg >> 3) + (wg >> 3);
  const int m0 = (wg % nbx) << 8;
  const int n0 = (wg / nbx) << 8;

  // staging source (per-lane): row w*8 + l/8 within 64-row instr block,
  // col slot = (l&7) ^ (l>>3)  [inverse of read-side XOR since row&7 = l>>3]
  const int srow = (w << 3) + (l >> 3);
  const int scol = (((l & 7) ^ (l >> 3)) << 3);
  const u16* gA = A + (size_t)(m0 + srow) * K + scol;
  const u16* gB = Bt + (size_t)(n0 + srow) * K + scol;
  const size_t rowstep = (size_t)64 * K;  // 64 rows

#define STAGE(gbase, smem, buf, half, kt)                                      \
  {                                                                            \
    const u16* _s = (gbase) + (size_t)(kt) * 64 + (size_t)((half) * 2) * rowstep; \
    u16* _d = &smem[buf][(half) * 8192 + (w << 9)];                            \
    GLD(_s, _d);                                                               \
    GLD(_s + rowstep, _d + 4096);                                              \
  }

  const int wm = (w >> 2) << 7;  // 0 / 128
  const int wn = (w & 3) << 6;   // 0,64,128,192
  const int fr = l & 15;
  const int lh = l >> 4;
  const int axo = ((lh ^ (l & 7)) & 7) << 3;  // u16 col offset, ks=0; ks=1: ^32

  f32x4 acc[8][4] = {};
  short8 Ar[4][2], Bn0[2][2], Bn1[2][2];
  const int NT = K >> 6;

#define LDA(c, msub)                                                           \
  _Pragma("unroll") for (int i = 0; i < 4; ++i) {                              \
    int r = wm + (msub) * 64 + i * 16 + fr;                                    \
    Ar[i][0] = *(const short8*)&sA[c][r * 64 + axo];                           \
    Ar[i][1] = *(const short8*)&sA[c][r * 64 + (32 ^ axo)];                    \
  }
#define LDB(c, dst, nsub)                                                      \
  _Pragma("unroll") for (int jf = 0; jf < 2; ++jf) {                           \
    int r = wn + (nsub) * 32 + jf * 16 + fr;                                   \
    dst[jf][0] = *(const short8*)&sB[c][r * 64 + axo];                         \
    dst[jf][1] = *(const short8*)&sB[c][r * 64 + (32 ^ axo)];                  \
  }
#define MM(mb, nb, BREG)                                                       \
  _Pragma("unroll") for (int i = 0; i < 4; ++i)                                \
  _Pragma("unroll") for (int jf = 0; jf < 2; ++jf)                             \
  _Pragma("unroll") for (int ks = 0; ks < 2; ++ks)                             \
    acc[(mb) + i][(nb) + jf] = __builtin_amdgcn_mfma_f32_16x16x32_bf16(        \
        Ar[i][ks], BREG[jf][ks], acc[(mb) + i][(nb) + jf], 0, 0, 0);
#define BAR_LGKM()                                                             \
  __builtin_amdgcn_sched_barrier(0);                                           \
  __builtin_amdgcn_s_barrier();                                                \
  asm volatile("s_waitcnt lgkmcnt(0)" ::: "memory");                           \
  __builtin_amdgcn_sched_barrier(0);
#define TRAIL_BAR()                                                            \
  __builtin_amdgcn_sched_barrier(0);                                           \
  __builtin_amdgcn_s_barrier();

  // ---- prologue: tile0 all halves into buf0; tile1 B-halves into buf1 ----
  STAGE(gA, sA, 0, 0, 0);
  STAGE(gA, sA, 0, 1, 0);
  STAGE(gB, sB, 0, 0, 0);
  STAGE(gB, sB, 0, 1, 0);
  if (NT > 1) {
    STAGE(gB, sB, 1, 0, 1);
    STAGE(gB, sB, 1, 1, 1);
    asm volatile("s_waitcnt vmcnt(4)" ::: "memory");
  } else {
    asm volatile("s_waitcnt vmcnt(0)" ::: "memory");
  }
  __builtin_amdgcn_s_barrier();

  for (int t = 0; t < NT; ++t) {
    const int c = t & 1;
    // P0: Q0 = (M0,N0)
    LDA(c, 0);
    LDB(c, Bn0, 0);
    if (t + 1 < NT) STAGE(gA, sA, c ^ 1, 0, t + 1);
    BAR_LGKM();
    __builtin_amdgcn_s_setprio(1);
    MM(0, 0, Bn0);
    __builtin_amdgcn_s_setprio(0);
    TRAIL_BAR();
    // P1: Q1 = (M0,N1)
    LDB(c, Bn1, 1);
    if (t + 1 < NT) STAGE(gA, sA, c ^ 1, 1, t + 1);
    BAR_LGKM();
    __builtin_amdgcn_s_setprio(1);
    MM(0, 2, Bn1);
    __builtin_amdgcn_s_setprio(0);
    TRAIL_BAR();
    // P2: Q2 = (M1,N0)
    LDA(c, 1);
    if (t + 2 < NT) STAGE(gB, sB, c, 0, t + 2);
    BAR_LGKM();
    __builtin_amdgcn_s_setprio(1);
    MM(4, 0, Bn0);
    __builtin_amdgcn_s_setprio(0);
    TRAIL_BAR();
    // P3: Q3 = (M1,N1)
    if (t + 2 < NT) STAGE(gB, sB, c, 1, t + 2);
    __builtin_amdgcn_sched_barrier(0);
    __builtin_amdgcn_s_barrier();
    __builtin_amdgcn_sched_barrier(0);
    __builtin_amdgcn_s_setprio(1);
    MM(4, 2, Bn1);
    __builtin_amdgcn_s_setprio(0);
    __builtin_amdgcn_sched_barrier(0);
    if (t + 2 < NT) {
      asm volatile("s_waitcnt vmcnt(4)" ::: "memory");
    } else if (t + 1 < NT) {
      asm volatile("s_waitcnt vmcnt(0)" ::: "memory");
    }
    __builtin_amdgcn_s_barrier();
  }

  // epilogue: C/D map col=lane&15, row=(lane>>4)*4+q
#pragma unroll
  for (int mi = 0; mi < 8; ++mi) {
#pragma unroll
    for (int nj = 0; nj < 4; ++nj) {
      const int row = m0 + wm + mi * 16 + lh * 4;
      const int col = n0 + wn + nj * 16 + fr;
#pragma unroll
      for (int q = 0; q < 4; ++q) {
        const int m = row + q;
        float v = acc[mi][nj][q];
        if constexpr (EPI == 0) {  // u = gamma*(v+bias) -> bf16
          int h = col & 511;
          float bias = (col < 512) ? e1[h] : e2[h];
          ((u16*)Cv)[(size_t)m * N + col] = f2bf(e0[h] * (v + bias));
        } else if constexpr (EPI == 1) {  // y = v + cr - ci -> bf16
          ((u16*)Cv)[(size_t)m * N + col] = f2bf(v + e0[col] - e1[col]);
        } else if constexpr (EPI == 2) {  // h1 = v + b1 -> bf16
          ((u16*)Cv)[(size_t)m * N + col] = f2bf(v + e0[col]);
        } else {  // out = v + b2 -> f32
          ((float*)Cv)[(size_t)m * N + col] = v + e0[col];
        }
      }
    }
  }
#undef STAGE
#undef LDA
#undef LDB
#undef MM
#undef BAR_LGKM
#undef TRAIL_BAR
}

// ---------------- scan (chunked: 16 chunks x 128 steps) ----------------
// u layout: [m=b*2048+t][1024] bf16, cols 0..511 = ur, 512..1023 = ui

__global__ __launch_bounds__(256) void scan_fin(const u16* __restrict__ u,
                                                const float* __restrict__ cst,
                                                float2* __restrict__ fin) {
  int g = blockIdx.x * 256 + threadIdx.x;  // 131072
  int h = g & 511, b = (g >> 9) & 15, c = g >> 13;
  float lr = cst[h], li = cst[512 + h];
  const u16* pr = u + ((size_t)(b * 2048 + c * 128)) * 1024 + h;
  float fr = 0.f, fi = 0.f;
#pragma unroll 4
  for (int j = 0; j < 128; ++j) {
    float ur = bf2f(pr[0]), ui = bf2f(pr[512]);
    float nr = fmaf(lr, fr, fmaf(-li, fi, ur));
    float ni = fmaf(lr, fi, fmaf(li, fr, ui));
    fr = nr;
    fi = ni;
    pr += 1024;
  }
  fin[(size_t)(c * 16 + b) * 512 + h] = make_float2(fr, fi);
}

__global__ __launch_bounds__(256) void scan_carry(const float2* __restrict__ fin,
                                                  const float* __restrict__ cst,
                                                  float2* __restrict__ carry) {
  int g = blockIdx.x * 256 + threadIdx.x;  // 8192
  int h = g & 511, b = g >> 9;
  float lr = cst[1024 + h], li = cst[1536 + h];  // lam^128
  float sr = 0.f, si = 0.f;
#pragma unroll
  for (int c = 0; c < 16; ++c) {
    size_t idx = (size_t)(c * 16 + b) * 512 + h;
    carry[idx] = make_float2(sr, si);
    float2 f = fin[idx];
    float nr = fmaf(lr, sr, fmaf(-li, si, f.x));
    float ni = fmaf(lr, si, fmaf(li, sr, f.y));
    sr = nr;
    si = ni;
  }
}

__global__ __launch_bounds__(256) void scan_out(const u16* __restrict__ u,
                                                const float* __restrict__ cst,
                                                const float2* __restrict__ carry,
                                                u16* __restrict__ hcat) {
  int g = blockIdx.x * 256 + threadIdx.x;
  int h = g & 511, b = (g >> 9) & 15, c = g >> 13;
  float lr = cst[h], li = cst[512 + h];
  size_t mb = ((size_t)(b * 2048 + c * 128)) * 1024;
  const u16* pr = u + mb + h;
  u16* qr = hcat + mb + h;
  float2 s0 = carry[(size_t)(c * 16 + b) * 512 + h];
  float sr = s0.x, si = s0.y;
#pragma unroll 4
  for (int j = 0; j < 128; ++j) {
    float ur = bf2f(pr[0]), ui = bf2f(pr[512]);
    float nr = fmaf(lr, sr, fmaf(-li, si, ur));
    float ni = fmaf(lr, si, fmaf(li, sr, ui));
    sr = nr;
    si = ni;
    qr[0] = f2bf(sr);
    qr[512] = f2bf(si);
    pr += 1024;
    qr += 1024;
  }
}

// ---------------- LayerNorm (bf16 in, bf16 out) ----------------
__global__ __launch_bounds__(256) void ln_bf(const u16* __restrict__ y,
                                             const float* __restrict__ sc,
                                             const float* __restrict__ bs,
                                             u16* __restrict__ out) {
  int row = blockIdx.x * 4 + (threadIdx.x >> 6);
  int lane = threadIdx.x & 63;
  ushort8 v = ((const ushort8*)(y + (size_t)row * 512))[lane];
  float f[8];
#pragma unroll
  for (int i = 0; i < 8; ++i) f[i] = bf2f(v[i]);
  float s = 0.f, q = 0.f;
#pragma unroll
  for (int i = 0; i < 8; ++i) {
    s += f[i];
    q += f[i] * f[i];
  }
#pragma unroll
  for (int m = 32; m >= 1; m >>= 1) {
    s += __shfl_xor(s, m, 64);
    q += __shfl_xor(q, m, 64);
  }
  float mean = s * (1.f / 512.f);
  float var = q * (1.f / 512.f) - mean * mean;
  float rstd = rsqrtf(var + 1e-6f);
  int jb = lane * 8;
  const float4* scp = (const float4*)(sc + jb);
  const float4* bsp = (const float4*)(bs + jb);
  float4 s0 = scp[0], s1 = scp[1], b0 = bsp[0], b1 = bsp[1];
  ushort8 o;
  o[0] = f2bf((f[0] - mean) * rstd * s0.x + b0.x);
  o[1] = f2bf((f[1] - mean) * rstd * s0.y + b0.y);
  o[2] = f2bf((f[2] - mean) * rstd * s0.z + b0.z);
  o[3] = f2bf((f[3] - mean) * rstd * s0.w + b0.w);
  o[4] = f2bf((f[4] - mean) * rstd * s1.x + b1.x);
  o[5] = f2bf((f[5] - mean) * rstd * s1.y + b1.y);
  o[6] = f2bf((f[6] - mean) * rstd * s1.z + b1.z);
  o[7] = f2bf((f[7] - mean) * rstd * s1.w + b1.w);
  ((ushort8*)(out + (size_t)row * 512))[lane] = o;
}

// ---------------- launch ----------------
extern "C" void kernel_launch(void* const* d_in, const int* in_sizes, int n_in,
                              void* d_out, int out_size, void* d_ws,
                              size_t ws_size, hipStream_t stream) {
  const float* x   = (const float*)d_in[0];
  const float* nu  = (const float*)d_in[1];
  const float* th  = (const float*)d_in[2];
  const float* gl  = (const float*)d_in[3];
  const float* Br  = (const float*)d_in[4];
  const float* br  = (const float*)d_in[5];
  const float* Bi  = (const float*)d_in[6];
  const float* bi  = (const float*)d_in[7];
  const float* Cr  = (const float*)d_in[8];
  const float* cr  = (const float*)d_in[9];
  const float* Ci  = (const float*)d_in[10];
  const float* ci  = (const float*)d_in[11];
  const float* lns = (const float*)d_in[12];
  const float* lnb = (const float*)d_in[13];
  const float* W1  = (const float*)d_in[14];
  const float* b1  = (const float*)d_in[15];
  const float* W2  = (const float*)d_in[16];
  const float* b2  = (const float*)d_in[17];

  char* ws = (char*)d_ws;
  size_t off = 0;
  auto alloc = [&](size_t bytes) {
    char* p = ws + off;
    off += (bytes + 255) & ~(size_t)255;
    return p;
  };
  float* cst  = (float*)alloc(2560 * 4);
  u16* BcT    = (u16*)alloc((size_t)1024 * 512 * 2);   // [n<512:Br | n>=512:Bi][k]
  u16* WcT    = (u16*)alloc((size_t)512 * 1024 * 2);   // [n][k<512:Cr | k>=512:-Ci]
  u16* W1T    = (u16*)alloc((size_t)2048 * 512 * 2);
  u16* W2T    = (u16*)alloc((size_t)512 * 2048 * 2);
  float2* fin = (float2*)alloc((size_t)16 * 16 * 512 * 8);
  float2* car = (float2*)alloc((size_t)16 * 16 * 512 * 8);
  u16* xb     = (u16*)alloc((size_t)32768 * 512 * 2);   // x bf16; later ybn
  u16* big1   = (u16*)alloc((size_t)32768 * 1024 * 2);  // u ; then y bf16 ; then h1 lo
  u16* big2   = (u16*)alloc((size_t)32768 * 1024 * 2);  // hcat ; then h1 hi
  (void)in_sizes; (void)n_in; (void)out_size; (void)ws_size;

  // prep
  k_const<<<dim3(1), dim3(512), 0, stream>>>(nu, th, gl, cst);
  transpose_cvt<<<dim3(16, 16), dim3(256), 0, stream>>>(Br, BcT, 512, 512, 512, 1.f);
  transpose_cvt<<<dim3(16, 16), dim3(256), 0, stream>>>(Bi, BcT + 512 * 512, 512, 512, 512, 1.f);
  transpose_cvt<<<dim3(16, 16), dim3(256), 0, stream>>>(Cr, WcT, 512, 512, 1024, 1.f);
  transpose_cvt<<<dim3(16, 16), dim3(256), 0, stream>>>(Ci, WcT + 512, 512, 512, 1024, -1.f);
  transpose_cvt<<<dim3(64, 16), dim3(256), 0, stream>>>(W1, W1T, 512, 2048, 512, 1.f);
  transpose_cvt<<<dim3(16, 64), dim3(256), 0, stream>>>(W2, W2T, 2048, 512, 2048, 1.f);
  cast_bf<<<dim3(8192), dim3(256), 0, stream>>>(x, xb);

  // G1: u = gamma*(x@[Br|Bi] + [br|bi]) -> bf16 big1 [32768][1024]
  gemm8p<0><<<dim3(128 * 4), dim3(512), 0, stream>>>(
      xb, BcT, (void*)big1, 32768, 1024, 512, cst + 2048, br, bi);
  // scan
  scan_fin<<<dim3(512), dim3(256), 0, stream>>>(big1, cst, fin);
  scan_carry<<<dim3(32), dim3(256), 0, stream>>>(fin, cst, car);
  scan_out<<<dim3(512), dim3(256), 0, stream>>>(big1, cst, car, big2);
  // G2: y = [hr|hi] @ [Cr;-Ci] + (cr-ci) -> bf16 into big1 slot
  gemm8p<1><<<dim3(128 * 2), dim3(512), 0, stream>>>(
      big2, WcT, (void*)big1, 32768, 512, 1024, cr, ci, nullptr);
  // LN -> bf16 into xb slot
  ln_bf<<<dim3(8192), dim3(256), 0, stream>>>(big1, lns, lnb, xb);
  // G3: h1 = ybn@W1 + b1 -> bf16 into big1+big2 (contiguous)
  gemm8p<2><<<dim3(128 * 8), dim3(512), 0, stream>>>(
      xb, W1T, (void*)big1, 32768, 2048, 512, b1, nullptr, nullptr);
  // G4: out = h1@W2 + b2 -> f32 d_out
  gemm8p<3><<<dim3(128 * 2), dim3(512), 0, stream>>>(
      big1, W2T, d_out, 32768, 512, 2048, b2, nullptr, nullptr);
}

// Round 3
// 338.010 us; speedup vs baseline: 1.1311x; 1.0524x over previous
//
#include <hip/hip_runtime.h>

typedef unsigned short u16;
typedef __attribute__((ext_vector_type(8))) short short8;
typedef __attribute__((ext_vector_type(4))) float f32x4;
typedef __attribute__((ext_vector_type(8))) unsigned short ushort8;

__device__ __forceinline__ u16 f2bf(float f) {
  unsigned u = __float_as_uint(f);
  u += 0x7FFFu + ((u >> 16) & 1u);
  return (u16)(u >> 16);
}
__device__ __forceinline__ float bf2f(u16 h) {
  return __uint_as_float(((unsigned)h) << 16);
}

#define GLD(gsrc, ldst)                                                        \
  __builtin_amdgcn_global_load_lds(                                            \
      (const __attribute__((address_space(1))) void*)(gsrc),                   \
      (__attribute__((address_space(3))) void*)(ldst), 16, 0, 0)

// ---------------- prep kernels ----------------

__global__ void k_const(const float* __restrict__ nu_log,
                        const float* __restrict__ theta_log,
                        const float* __restrict__ gamma_log,
                        float* __restrict__ cst) {
  int h = threadIdx.x;  // 512 threads
  float mag = expf(-expf(nu_log[h]));
  float th  = expf(theta_log[h]);
  float lr = mag * cosf(th), li = mag * sinf(th);
  cst[h] = lr;
  cst[512 + h] = li;
  float pr = lr, pi = li;
#pragma unroll
  for (int i = 0; i < 7; ++i) {  // lam^128 via 7 squarings
    float nr = pr * pr - pi * pi;
    pi = 2.f * pr * pi;
    pr = nr;
  }
  cst[1024 + h] = pr;
  cst[1536 + h] = pi;
  cst[2048 + h] = expf(gamma_log[h]);
}

// dst[c*DL + r] = bf16(sgn * src[r*C + c]) ; tiled 32x32, 256 threads
__global__ __launch_bounds__(256) void transpose_cvt(
    const float* __restrict__ src, u16* __restrict__ dst, int R, int C, int DL,
    float sgn) {
  __shared__ float t[32][33];
  int bc = blockIdx.x << 5, brr = blockIdx.y << 5;
  int tx = threadIdx.x & 31, ty = threadIdx.x >> 5;  // ty 0..7
#pragma unroll
  for (int i = 0; i < 32; i += 8)
    t[ty + i][tx] = src[(size_t)(brr + ty + i) * C + bc + tx];
  __syncthreads();
#pragma unroll
  for (int i = 0; i < 32; i += 8)
    dst[(size_t)(bc + ty + i) * DL + brr + tx] = f2bf(sgn * t[tx][ty + i]);
}

// f32 -> bf16, 8 elems/thread
__global__ __launch_bounds__(256) void cast_bf(const float* __restrict__ in,
                                               u16* __restrict__ out) {
  int g = blockIdx.x * 256 + threadIdx.x;
  const float4* p = (const float4*)in + (size_t)g * 2;
  float4 a = p[0], b = p[1];
  ushort8 o;
  o[0] = f2bf(a.x); o[1] = f2bf(a.y); o[2] = f2bf(a.z); o[3] = f2bf(a.w);
  o[4] = f2bf(b.x); o[5] = f2bf(b.y); o[6] = f2bf(b.z); o[7] = f2bf(b.w);
  ((ushort8*)out)[g] = o;
}

// ---------------- GEMM: 256x256 tile, BK=64, 8-phase counted-vmcnt ----------
// C[M,N] = A[M,K] @ Bt[N,K]^T ; A,Bt bf16 row-major.
// 8 waves (2M x 4N), per-wave 128x64 out, mfma_f32_16x16x32_bf16.
// LDS 128 KiB double-buffered, XOR-swizzled (slot ^= row&7) with linear
// global_load_lds dest + pre-swizzled global source (rule #21).
// Grid: XCD-contiguous chunks, n-FASTEST inside a chunk so consecutive WGs
// share the A panel in the XCD's L2 (round-2 post-mortem: m-fastest caused
// 4x A over-fetch, FETCH 135 MB vs 36 ideal, staging at HBM latency).
template <int EPI>
__global__ __launch_bounds__(512, 2) void gemm8p(
    const u16* __restrict__ A, const u16* __restrict__ Bt, void* __restrict__ Cv,
    int M, int N, int K, const float* __restrict__ e0,
    const float* __restrict__ e1, const float* __restrict__ e2) {
  __shared__ u16 sA[2][256 * 64];
  __shared__ u16 sB[2][256 * 64];
  const int tid = threadIdx.x;
  const int w = tid >> 6, l = tid & 63;

  // XCD-aware bijective swizzle (nwg % 8 == 0 for all our shapes),
  // then n-fastest within the chunk (nby is a power of two).
  const int nby = N >> 8;
  const int nwg = gridDim.x;
  int wg = blockIdx.x;
  wg = (wg & 7) * (nwg >> 3) + (wg >> 3);
  const int n0 = (wg & (nby - 1)) << 8;
  const int m0 = (wg >> __builtin_ctz(nby)) << 8;

  // staging source (per-lane): row w*8 + l/8 within 64-row instr block,
  // col slot = (l&7) ^ (l>>3)  [inverse of read-side XOR since row&7 = l>>3]
  const int srow = (w << 3) + (l >> 3);
  const int scol = (((l & 7) ^ (l >> 3)) << 3);
  const u16* gA = A + (size_t)(m0 + srow) * K + scol;
  const u16* gB = Bt + (size_t)(n0 + srow) * K + scol;
  const size_t rowstep = (size_t)64 * K;  // 64 rows

#define STAGE(gbase, smem, buf, half, kt)                                      \
  {                                                                            \
    const u16* _s = (gbase) + (size_t)(kt) * 64 + (size_t)((half) * 2) * rowstep; \
    u16* _d = &smem[buf][(half) * 8192 + (w << 9)];                            \
    GLD(_s, _d);                                                               \
    GLD(_s + rowstep, _d + 4096);                                              \
  }

  const int wm = (w >> 2) << 7;  // 0 / 128
  const int wn = (w & 3) << 6;   // 0,64,128,192
  const int fr = l & 15;
  const int lh = l >> 4;
  const int axo = ((lh ^ (l & 7)) & 7) << 3;  // u16 col offset, ks=0; ks=1: ^32

  f32x4 acc[8][4] = {};
  short8 Ar[4][2], Bn0[2][2], Bn1[2][2];
  const int NT = K >> 6;

#define LDA(c, msub)                                                           \
  _Pragma("unroll") for (int i = 0; i < 4; ++i) {                              \
    int r = wm + (msub) * 64 + i * 16 + fr;                                    \
    Ar[i][0] = *(const short8*)&sA[c][r * 64 + axo];                           \
    Ar[i][1] = *(const short8*)&sA[c][r * 64 + (32 ^ axo)];                    \
  }
#define LDB(c, dst, nsub)                                                      \
  _Pragma("unroll") for (int jf = 0; jf < 2; ++jf) {                           \
    int r = wn + (nsub) * 32 + jf * 16 + fr;                                   \
    dst[jf][0] = *(const short8*)&sB[c][r * 64 + axo];                         \
    dst[jf][1] = *(const short8*)&sB[c][r * 64 + (32 ^ axo)];                  \
  }
#define MM(mb, nb, BREG)                                                       \
  _Pragma("unroll") for (int i = 0; i < 4; ++i)                                \
  _Pragma("unroll") for (int jf = 0; jf < 2; ++jf)                             \
  _Pragma("unroll") for (int ks = 0; ks < 2; ++ks)                             \
    acc[(mb) + i][(nb) + jf] = __builtin_amdgcn_mfma_f32_16x16x32_bf16(        \
        Ar[i][ks], BREG[jf][ks], acc[(mb) + i][(nb) + jf], 0, 0, 0);
#define BAR_LGKM()                                                             \
  __builtin_amdgcn_sched_barrier(0);                                           \
  __builtin_amdgcn_s_barrier();                                                \
  asm volatile("s_waitcnt lgkmcnt(0)" ::: "memory");                           \
  __builtin_amdgcn_sched_barrier(0);
#define TRAIL_BAR()                                                            \
  __builtin_amdgcn_sched_barrier(0);                                           \
  __builtin_amdgcn_s_barrier();

  // ---- prologue: tile0 all halves into buf0; tile1 B-halves into buf1 ----
  STAGE(gA, sA, 0, 0, 0);
  STAGE(gA, sA, 0, 1, 0);
  STAGE(gB, sB, 0, 0, 0);
  STAGE(gB, sB, 0, 1, 0);
  if (NT > 1) {
    STAGE(gB, sB, 1, 0, 1);
    STAGE(gB, sB, 1, 1, 1);
    asm volatile("s_waitcnt vmcnt(4)" ::: "memory");
  } else {
    asm volatile("s_waitcnt vmcnt(0)" ::: "memory");
  }
  __builtin_amdgcn_s_barrier();

  for (int t = 0; t < NT; ++t) {
    const int c = t & 1;
    // P0: Q0 = (M0,N0)
    LDA(c, 0);
    LDB(c, Bn0, 0);
    if (t + 1 < NT) STAGE(gA, sA, c ^ 1, 0, t + 1);
    BAR_LGKM();
    __builtin_amdgcn_s_setprio(1);
    MM(0, 0, Bn0);
    __builtin_amdgcn_s_setprio(0);
    TRAIL_BAR();
    // P1: Q1 = (M0,N1)
    LDB(c, Bn1, 1);
    if (t + 1 < NT) STAGE(gA, sA, c ^ 1, 1, t + 1);
    BAR_LGKM();
    __builtin_amdgcn_s_setprio(1);
    MM(0, 2, Bn1);
    __builtin_amdgcn_s_setprio(0);
    TRAIL_BAR();
    // P2: Q2 = (M1,N0)
    LDA(c, 1);
    if (t + 2 < NT) STAGE(gB, sB, c, 0, t + 2);
    BAR_LGKM();
    __builtin_amdgcn_s_setprio(1);
    MM(4, 0, Bn0);
    __builtin_amdgcn_s_setprio(0);
    TRAIL_BAR();
    // P3: Q3 = (M1,N1)
    if (t + 2 < NT) STAGE(gB, sB, c, 1, t + 2);
    __builtin_amdgcn_sched_barrier(0);
    __builtin_amdgcn_s_barrier();
    __builtin_amdgcn_sched_barrier(0);
    __builtin_amdgcn_s_setprio(1);
    MM(4, 2, Bn1);
    __builtin_amdgcn_s_setprio(0);
    __builtin_amdgcn_sched_barrier(0);
    if (t + 2 < NT) {
      asm volatile("s_waitcnt vmcnt(4)" ::: "memory");
    } else if (t + 1 < NT) {
      asm volatile("s_waitcnt vmcnt(0)" ::: "memory");
    }
    __builtin_amdgcn_s_barrier();
  }

  // epilogue: C/D map col=lane&15, row=(lane>>4)*4+q
#pragma unroll
  for (int mi = 0; mi < 8; ++mi) {
#pragma unroll
    for (int nj = 0; nj < 4; ++nj) {
      const int row = m0 + wm + mi * 16 + lh * 4;
      const int col = n0 + wn + nj * 16 + fr;
#pragma unroll
      for (int q = 0; q < 4; ++q) {
        const int m = row + q;
        float v = acc[mi][nj][q];
        if constexpr (EPI == 0) {  // u = gamma*(v+bias) -> bf16
          int h = col & 511;
          float bias = (col < 512) ? e1[h] : e2[h];
          ((u16*)Cv)[(size_t)m * N + col] = f2bf(e0[h] * (v + bias));
        } else if constexpr (EPI == 1) {  // y = v + cr - ci -> bf16
          ((u16*)Cv)[(size_t)m * N + col] = f2bf(v + e0[col] - e1[col]);
        } else if constexpr (EPI == 2) {  // h1 = v + b1 -> bf16
          ((u16*)Cv)[(size_t)m * N + col] = f2bf(v + e0[col]);
        } else {  // out = v + b2 -> f32
          ((float*)Cv)[(size_t)m * N + col] = v + e0[col];
        }
      }
    }
  }
#undef STAGE
#undef LDA
#undef LDB
#undef MM
#undef BAR_LGKM
#undef TRAIL_BAR
}

// ---------------- scan (chunked: 16 chunks x 128 steps) ----------------
// u layout: [m=b*2048+t][1024] bf16, cols 0..511 = ur, 512..1023 = ui

__global__ __launch_bounds__(256) void scan_fin(const u16* __restrict__ u,
                                                const float* __restrict__ cst,
                                                float2* __restrict__ fin) {
  int g = blockIdx.x * 256 + threadIdx.x;  // 131072
  int h = g & 511, b = (g >> 9) & 15, c = g >> 13;
  float lr = cst[h], li = cst[512 + h];
  const u16* pr = u + ((size_t)(b * 2048 + c * 128)) * 1024 + h;
  float fr = 0.f, fi = 0.f;
#pragma unroll 4
  for (int j = 0; j < 128; ++j) {
    float ur = bf2f(pr[0]), ui = bf2f(pr[512]);
    float nr = fmaf(lr, fr, fmaf(-li, fi, ur));
    float ni = fmaf(lr, fi, fmaf(li, fr, ui));
    fr = nr;
    fi = ni;
    pr += 1024;
  }
  fin[(size_t)(c * 16 + b) * 512 + h] = make_float2(fr, fi);
}

__global__ __launch_bounds__(256) void scan_carry(const float2* __restrict__ fin,
                                                  const float* __restrict__ cst,
                                                  float2* __restrict__ carry) {
  int g = blockIdx.x * 256 + threadIdx.x;  // 8192
  int h = g & 511, b = g >> 9;
  float lr = cst[1024 + h], li = cst[1536 + h];  // lam^128
  float sr = 0.f, si = 0.f;
#pragma unroll
  for (int c = 0; c < 16; ++c) {
    size_t idx = (size_t)(c * 16 + b) * 512 + h;
    carry[idx] = make_float2(sr, si);
    float2 f = fin[idx];
    float nr = fmaf(lr, sr, fmaf(-li, si, f.x));
    float ni = fmaf(lr, si, fmaf(li, sr, f.y));
    sr = nr;
    si = ni;
  }
}

__global__ __launch_bounds__(256) void scan_out(const u16* __restrict__ u,
                                                const float* __restrict__ cst,
                                                const float2* __restrict__ carry,
                                                u16* __restrict__ hcat) {
  int g = blockIdx.x * 256 + threadIdx.x;
  int h = g & 511, b = (g >> 9) & 15, c = g >> 13;
  float lr = cst[h], li = cst[512 + h];
  size_t mb = ((size_t)(b * 2048 + c * 128)) * 1024;
  const u16* pr = u + mb + h;
  u16* qr = hcat + mb + h;
  float2 s0 = carry[(size_t)(c * 16 + b) * 512 + h];
  float sr = s0.x, si = s0.y;
#pragma unroll 4
  for (int j = 0; j < 128; ++j) {
    float ur = bf2f(pr[0]), ui = bf2f(pr[512]);
    float nr = fmaf(lr, sr, fmaf(-li, si, ur));
    float ni = fmaf(lr, si, fmaf(li, sr, ui));
    sr = nr;
    si = ni;
    qr[0] = f2bf(sr);
    qr[512] = f2bf(si);
    pr += 1024;
    qr += 1024;
  }
}

// ---------------- LayerNorm (bf16 in, bf16 out) ----------------
__global__ __launch_bounds__(256) void ln_bf(const u16* __restrict__ y,
                                             const float* __restrict__ sc,
                                             const float* __restrict__ bs,
                                             u16* __restrict__ out) {
  int row = blockIdx.x * 4 + (threadIdx.x >> 6);
  int lane = threadIdx.x & 63;
  ushort8 v = ((const ushort8*)(y + (size_t)row * 512))[lane];
  float f[8];
#pragma unroll
  for (int i = 0; i < 8; ++i) f[i] = bf2f(v[i]);
  float s = 0.f, q = 0.f;
#pragma unroll
  for (int i = 0; i < 8; ++i) {
    s += f[i];
    q += f[i] * f[i];
  }
#pragma unroll
  for (int m = 32; m >= 1; m >>= 1) {
    s += __shfl_xor(s, m, 64);
    q += __shfl_xor(q, m, 64);
  }
  float mean = s * (1.f / 512.f);
  float var = q * (1.f / 512.f) - mean * mean;
  float rstd = rsqrtf(var + 1e-6f);
  int jb = lane * 8;
  const float4* scp = (const float4*)(sc + jb);
  const float4* bsp = (const float4*)(bs + jb);
  float4 s0 = scp[0], s1 = scp[1], b0 = bsp[0], b1 = bsp[1];
  ushort8 o;
  o[0] = f2bf((f[0] - mean) * rstd * s0.x + b0.x);
  o[1] = f2bf((f[1] - mean) * rstd * s0.y + b0.y);
  o[2] = f2bf((f[2] - mean) * rstd * s0.z + b0.z);
  o[3] = f2bf((f[3] - mean) * rstd * s0.w + b0.w);
  o[4] = f2bf((f[4] - mean) * rstd * s1.x + b1.x);
  o[5] = f2bf((f[5] - mean) * rstd * s1.y + b1.y);
  o[6] = f2bf((f[6] - mean) * rstd * s1.z + b1.z);
  o[7] = f2bf((f[7] - mean) * rstd * s1.w + b1.w);
  ((ushort8*)(out + (size_t)row * 512))[lane] = o;
}

// ---------------- launch ----------------
extern "C" void kernel_launch(void* const* d_in, const int* in_sizes, int n_in,
                              void* d_out, int out_size, void* d_ws,
                              size_t ws_size, hipStream_t stream) {
  const float* x   = (const float*)d_in[0];
  const float* nu  = (const float*)d_in[1];
  const float* th  = (const float*)d_in[2];
  const float* gl  = (const float*)d_in[3];
  const float* Br  = (const float*)d_in[4];
  const float* br  = (const float*)d_in[5];
  const float* Bi  = (const float*)d_in[6];
  const float* bi  = (const float*)d_in[7];
  const float* Cr  = (const float*)d_in[8];
  const float* cr  = (const float*)d_in[9];
  const float* Ci  = (const float*)d_in[10];
  const float* ci  = (const float*)d_in[11];
  const float* lns = (const float*)d_in[12];
  const float* lnb = (const float*)d_in[13];
  const float* W1  = (const float*)d_in[14];
  const float* b1  = (const float*)d_in[15];
  const float* W2  = (const float*)d_in[16];
  const float* b2  = (const float*)d_in[17];

  char* ws = (char*)d_ws;
  size_t off = 0;
  auto alloc = [&](size_t bytes) {
    char* p = ws + off;
    off += (bytes + 255) & ~(size_t)255;
    return p;
  };
  float* cst  = (float*)alloc(2560 * 4);
  u16* BcT    = (u16*)alloc((size_t)1024 * 512 * 2);   // [n<512:Br | n>=512:Bi][k]
  u16* WcT    = (u16*)alloc((size_t)512 * 1024 * 2);   // [n][k<512:Cr | k>=512:-Ci]
  u16* W1T    = (u16*)alloc((size_t)2048 * 512 * 2);
  u16* W2T    = (u16*)alloc((size_t)512 * 2048 * 2);
  float2* fin = (float2*)alloc((size_t)16 * 16 * 512 * 8);
  float2* car = (float2*)alloc((size_t)16 * 16 * 512 * 8);
  u16* xb     = (u16*)alloc((size_t)32768 * 512 * 2);   // x bf16; later ybn
  u16* big1   = (u16*)alloc((size_t)32768 * 1024 * 2);  // u ; then y bf16 ; then h1 lo
  u16* big2   = (u16*)alloc((size_t)32768 * 1024 * 2);  // hcat ; then h1 hi
  (void)in_sizes; (void)n_in; (void)out_size; (void)ws_size;

  // prep
  k_const<<<dim3(1), dim3(512), 0, stream>>>(nu, th, gl, cst);
  transpose_cvt<<<dim3(16, 16), dim3(256), 0, stream>>>(Br, BcT, 512, 512, 512, 1.f);
  transpose_cvt<<<dim3(16, 16), dim3(256), 0, stream>>>(Bi, BcT + 512 * 512, 512, 512, 512, 1.f);
  transpose_cvt<<<dim3(16, 16), dim3(256), 0, stream>>>(Cr, WcT, 512, 512, 1024, 1.f);
  transpose_cvt<<<dim3(16, 16), dim3(256), 0, stream>>>(Ci, WcT + 512, 512, 512, 1024, -1.f);
  transpose_cvt<<<dim3(64, 16), dim3(256), 0, stream>>>(W1, W1T, 512, 2048, 512, 1.f);
  transpose_cvt<<<dim3(16, 64), dim3(256), 0, stream>>>(W2, W2T, 2048, 512, 2048, 1.f);
  cast_bf<<<dim3(8192), dim3(256), 0, stream>>>(x, xb);

  // G1: u = gamma*(x@[Br|Bi] + [br|bi]) -> bf16 big1 [32768][1024]
  gemm8p<0><<<dim3(128 * 4), dim3(512), 0, stream>>>(
      xb, BcT, (void*)big1, 32768, 1024, 512, cst + 2048, br, bi);
  // scan
  scan_fin<<<dim3(512), dim3(256), 0, stream>>>(big1, cst, fin);
  scan_carry<<<dim3(32), dim3(256), 0, stream>>>(fin, cst, car);
  scan_out<<<dim3(512), dim3(256), 0, stream>>>(big1, cst, car, big2);
  // G2: y = [hr|hi] @ [Cr;-Ci] + (cr-ci) -> bf16 into big1 slot
  gemm8p<1><<<dim3(128 * 2), dim3(512), 0, stream>>>(
      big2, WcT, (void*)big1, 32768, 512, 1024, cr, ci, nullptr);
  // LN -> bf16 into xb slot
  ln_bf<<<dim3(8192), dim3(256), 0, stream>>>(big1, lns, lnb, xb);
  // G3: h1 = ybn@W1 + b1 -> bf16 into big1+big2 (contiguous)
  gemm8p<2><<<dim3(128 * 8), dim3(512), 0, stream>>>(
      xb, W1T, (void*)big1, 32768, 2048, 512, b1, nullptr, nullptr);
  // G4: out = h1@W2 + b2 -> f32 d_out
  gemm8p<3><<<dim3(128 * 2), dim3(512), 0, stream>>>(
      big1, W2T, d_out, 32768, 512, 2048, b2, nullptr, nullptr);
}

// Round 4
// 318.839 us; speedup vs baseline: 1.1991x; 1.0601x over previous
//
#include <hip/hip_runtime.h>

typedef unsigned short u16;
typedef __attribute__((ext_vector_type(8))) short short8;
typedef __attribute__((ext_vector_type(4))) float f32x4;
typedef __attribute__((ext_vector_type(8))) unsigned short ushort8;

__device__ __forceinline__ u16 f2bf(float f) {
  unsigned u = __float_as_uint(f);
  u += 0x7FFFu + ((u >> 16) & 1u);
  return (u16)(u >> 16);
}
__device__ __forceinline__ float bf2f(u16 h) {
  return __uint_as_float(((unsigned)h) << 16);
}

#define GLD(gsrc, ldst)                                                        \
  __builtin_amdgcn_global_load_lds(                                            \
      (const __attribute__((address_space(1))) void*)(gsrc),                   \
      (__attribute__((address_space(3))) void*)(ldst), 16, 0, 0)

// B-row permutation for gemm_ln (freed-quarters contiguous):
// n -> ((nj>>1)<<7) | (wn<<5) | ((nj&1)<<4) | fr
__device__ __forceinline__ int permB(int n) {
  int wn = n >> 7, nj = (n >> 4) & 7, fr = n & 15;
  return ((nj >> 1) << 7) | (wn << 5) | ((nj & 1) << 4) | fr;
}

// ---------------- prep kernels ----------------

// lam, lam^32, gamma.  cst: [0..511] lam_r, [512..] lam_i,
// [1024..] lam32_r, [1536..] lam32_i, [2048..] gamma
__global__ void k_const(const float* __restrict__ nu_log,
                        const float* __restrict__ theta_log,
                        const float* __restrict__ gamma_log,
                        float* __restrict__ cst) {
  int h = threadIdx.x;  // 512
  float mag = expf(-expf(nu_log[h]));
  float th = expf(theta_log[h]);
  float lr = mag * cosf(th), li = mag * sinf(th);
  cst[h] = lr;
  cst[512 + h] = li;
  float pr = lr, pi = li;
#pragma unroll
  for (int i = 0; i < 5; ++i) {  // lam^32
    float nr = pr * pr - pi * pi;
    pi = 2.f * pr * pi;
    pr = nr;
  }
  cst[1024 + h] = pr;
  cst[1536 + h] = pi;
  cst[2048 + h] = expf(gamma_log[h]);
}

// All 6 weight transposes in ONE dispatch (3072 blocks).
// BcT rows interleaved: row 2h = Br[h], row 2h+1 = Bi[h]   ([1024][512])
// WcT rows permB(n), cols interleaved: 2k = Cr[k][n], 2k+1 = -Ci[k][n]
__global__ __launch_bounds__(256) void prep_all(
    const float* __restrict__ Br, const float* __restrict__ Bi,
    const float* __restrict__ Cr, const float* __restrict__ Ci,
    const float* __restrict__ W1, const float* __restrict__ W2,
    u16* __restrict__ BcT, u16* __restrict__ WcT, u16* __restrict__ W1T,
    u16* __restrict__ W2T) {
  __shared__ float t[32][33];
  int id = blockIdx.x;
  int which, tt;
  if (id < 1024) { which = id >> 8; tt = id & 255; }
  else if (id < 2048) { which = 4; tt = id - 1024; }
  else { which = 5; tt = id - 2048; }
  const float* src;
  int C, bx, by;
  if (which < 4) {
    src = (which == 0) ? Br : (which == 1) ? Bi : (which == 2) ? Cr : Ci;
    C = 512; bx = tt & 15; by = tt >> 4;
  } else if (which == 4) {
    src = W1; C = 2048; bx = tt & 63; by = tt >> 6;
  } else {
    src = W2; C = 512; bx = tt & 15; by = tt >> 4;
  }
  int bc = bx << 5, brr = by << 5;
  int tx = threadIdx.x & 31, ty = threadIdx.x >> 5;
#pragma unroll
  for (int i = 0; i < 32; i += 8)
    t[ty + i][tx] = src[(size_t)(brr + ty + i) * C + bc + tx];
  __syncthreads();
#pragma unroll
  for (int i = 0; i < 32; i += 8) {
    int cs = bc + ty + i, rs = brr + tx;
    float v = t[tx][ty + i];
    if (which == 0)      BcT[(size_t)(2 * cs) * 512 + rs] = f2bf(v);
    else if (which == 1) BcT[(size_t)(2 * cs + 1) * 512 + rs] = f2bf(v);
    else if (which == 2) WcT[(size_t)permB(cs) * 1024 + 2 * rs] = f2bf(v);
    else if (which == 3) WcT[(size_t)permB(cs) * 1024 + 2 * rs + 1] = f2bf(-v);
    else if (which == 4) W1T[(size_t)cs * 512 + rs] = f2bf(v);
    else                 W2T[(size_t)cs * 2048 + rs] = f2bf(v);
  }
}

// f32 -> bf16, 8 elems/thread
__global__ __launch_bounds__(256) void cast_bf(const float* __restrict__ in,
                                               u16* __restrict__ out) {
  int g = blockIdx.x * 256 + threadIdx.x;
  const float4* p = (const float4*)in + (size_t)g * 2;
  float4 a = p[0], b = p[1];
  ushort8 o;
  o[0] = f2bf(a.x); o[1] = f2bf(a.y); o[2] = f2bf(a.z); o[3] = f2bf(a.w);
  o[4] = f2bf(b.x); o[5] = f2bf(b.y); o[6] = f2bf(b.z); o[7] = f2bf(b.w);
  ((ushort8*)out)[g] = o;
}

// ---------------- GEMM: 256x256 tile, BK=64, 8-phase counted-vmcnt ----------
// EPI 0: u[col interleaved] = gamma[h]*(v + (col&1?bi:br)[h]), h=col>>1 -> bf16
// EPI 2: h1 = v + b1[col] -> bf16
// EPI 3: out = v + b2[col] -> f32
template <int EPI>
__global__ __launch_bounds__(512, 2) void gemm8p(
    const u16* __restrict__ A, const u16* __restrict__ Bt, void* __restrict__ Cv,
    int M, int N, int K, const float* __restrict__ e0,
    const float* __restrict__ e1, const float* __restrict__ e2) {
  __shared__ u16 sA[2][256 * 64];
  __shared__ u16 sB[2][256 * 64];
  const int tid = threadIdx.x;
  const int w = tid >> 6, l = tid & 63;

  const int nby = N >> 8;
  const int nwg = gridDim.x;
  int wg = blockIdx.x;
  wg = (wg & 7) * (nwg >> 3) + (wg >> 3);
  const int n0 = (wg & (nby - 1)) << 8;
  const int m0 = (wg >> __builtin_ctz(nby)) << 8;

  const int srow = (w << 3) + (l >> 3);
  const int scol = (((l & 7) ^ (l >> 3)) << 3);
  const u16* gA = A + (size_t)(m0 + srow) * K + scol;
  const u16* gB = Bt + (size_t)(n0 + srow) * K + scol;
  const size_t rowstep = (size_t)64 * K;

#define STAGE(gbase, smem, buf, half, kt)                                      \
  {                                                                            \
    const u16* _s = (gbase) + (size_t)(kt) * 64 + (size_t)((half) * 2) * rowstep; \
    u16* _d = &smem[buf][(half) * 8192 + (w << 9)];                            \
    GLD(_s, _d);                                                               \
    GLD(_s + rowstep, _d + 4096);                                              \
  }

  const int wm = (w >> 2) << 7;
  const int wn = (w & 3) << 6;
  const int fr = l & 15;
  const int lh = l >> 4;
  const int axo = ((lh ^ (l & 7)) & 7) << 3;

  f32x4 acc[8][4] = {};
  short8 Ar[4][2], Bn0[2][2], Bn1[2][2];
  const int NT = K >> 6;

#define LDA(c, msub)                                                           \
  _Pragma("unroll") for (int i = 0; i < 4; ++i) {                              \
    int r = wm + (msub) * 64 + i * 16 + fr;                                    \
    Ar[i][0] = *(const short8*)&sA[c][r * 64 + axo];                           \
    Ar[i][1] = *(const short8*)&sA[c][r * 64 + (32 ^ axo)];                    \
  }
#define LDB(c, dst, nsub)                                                      \
  _Pragma("unroll") for (int jf = 0; jf < 2; ++jf) {                           \
    int r = wn + (nsub) * 32 + jf * 16 + fr;                                   \
    dst[jf][0] = *(const short8*)&sB[c][r * 64 + axo];                         \
    dst[jf][1] = *(const short8*)&sB[c][r * 64 + (32 ^ axo)];                  \
  }
#define MM(mb, nb, BREG)                                                       \
  _Pragma("unroll") for (int i = 0; i < 4; ++i)                                \
  _Pragma("unroll") for (int jf = 0; jf < 2; ++jf)                             \
  _Pragma("unroll") for (int ks = 0; ks < 2; ++ks)                             \
    acc[(mb) + i][(nb) + jf] = __builtin_amdgcn_mfma_f32_16x16x32_bf16(        \
        Ar[i][ks], BREG[jf][ks], acc[(mb) + i][(nb) + jf], 0, 0, 0);
#define BAR_LGKM()                                                             \
  __builtin_amdgcn_sched_barrier(0);                                           \
  __builtin_amdgcn_s_barrier();                                                \
  asm volatile("s_waitcnt lgkmcnt(0)" ::: "memory");                           \
  __builtin_amdgcn_sched_barrier(0);
#define TRAIL_BAR()                                                            \
  __builtin_amdgcn_sched_barrier(0);                                           \
  __builtin_amdgcn_s_barrier();

  STAGE(gA, sA, 0, 0, 0);
  STAGE(gA, sA, 0, 1, 0);
  STAGE(gB, sB, 0, 0, 0);
  STAGE(gB, sB, 0, 1, 0);
  if (NT > 1) {
    STAGE(gB, sB, 1, 0, 1);
    STAGE(gB, sB, 1, 1, 1);
    asm volatile("s_waitcnt vmcnt(4)" ::: "memory");
  } else {
    asm volatile("s_waitcnt vmcnt(0)" ::: "memory");
  }
  __builtin_amdgcn_s_barrier();

  for (int t = 0; t < NT; ++t) {
    const int c = t & 1;
    LDA(c, 0);
    LDB(c, Bn0, 0);
    if (t + 1 < NT) STAGE(gA, sA, c ^ 1, 0, t + 1);
    BAR_LGKM();
    __builtin_amdgcn_s_setprio(1);
    MM(0, 0, Bn0);
    __builtin_amdgcn_s_setprio(0);
    TRAIL_BAR();
    LDB(c, Bn1, 1);
    if (t + 1 < NT) STAGE(gA, sA, c ^ 1, 1, t + 1);
    BAR_LGKM();
    __builtin_amdgcn_s_setprio(1);
    MM(0, 2, Bn1);
    __builtin_amdgcn_s_setprio(0);
    TRAIL_BAR();
    LDA(c, 1);
    if (t + 2 < NT) STAGE(gB, sB, c, 0, t + 2);
    BAR_LGKM();
    __builtin_amdgcn_s_setprio(1);
    MM(4, 0, Bn0);
    __builtin_amdgcn_s_setprio(0);
    TRAIL_BAR();
    if (t + 2 < NT) STAGE(gB, sB, c, 1, t + 2);
    __builtin_amdgcn_sched_barrier(0);
    __builtin_amdgcn_s_barrier();
    __builtin_amdgcn_sched_barrier(0);
    __builtin_amdgcn_s_setprio(1);
    MM(4, 2, Bn1);
    __builtin_amdgcn_s_setprio(0);
    __builtin_amdgcn_sched_barrier(0);
    if (t + 2 < NT) {
      asm volatile("s_waitcnt vmcnt(4)" ::: "memory");
    } else if (t + 1 < NT) {
      asm volatile("s_waitcnt vmcnt(0)" ::: "memory");
    }
    __builtin_amdgcn_s_barrier();
  }

#pragma unroll
  for (int mi = 0; mi < 8; ++mi) {
#pragma unroll
    for (int nj = 0; nj < 4; ++nj) {
      const int row = m0 + wm + mi * 16 + lh * 4;
      const int col = n0 + wn + nj * 16 + fr;
#pragma unroll
      for (int q = 0; q < 4; ++q) {
        const int m = row + q;
        float v = acc[mi][nj][q];
        if constexpr (EPI == 0) {
          int h = col >> 1;
          float bias = (col & 1) ? e2[h] : e1[h];
          ((u16*)Cv)[(size_t)m * N + col] = f2bf(e0[h] * (v + bias));
        } else if constexpr (EPI == 2) {
          ((u16*)Cv)[(size_t)m * N + col] = f2bf(v + e0[col]);
        } else {
          ((float*)Cv)[(size_t)m * N + col] = v + e0[col];
        }
      }
    }
  }
#undef STAGE
#undef LDA
#undef LDB
#undef MM
}

// ---------------- G2 + LayerNorm fused ----------------
// y = hcat @ WcT^T + (cr-ci); LN(y) -> ybn bf16 [32768][512]
// tile 128 x 512(full N), BK=32, NT=32, 8 waves (2M x 4N), per-wave 64x128.
__global__ __launch_bounds__(512, 2) void gemm_ln(
    const u16* __restrict__ A, const u16* __restrict__ Bp,
    u16* __restrict__ Out, const float* __restrict__ cr,
    const float* __restrict__ ci, const float* __restrict__ lns,
    const float* __restrict__ lnb) {
  __shared__ u16 sA[2][128 * 32];
  __shared__ u16 sB[2][512 * 32];
  __shared__ float lntab[128][4][2];
  const int tid = threadIdx.x, w = tid >> 6, l = tid & 63;
  int wg = blockIdx.x;
  wg = (wg & 7) * 32 + (wg >> 3);  // 256 WGs, bijective XCD swizzle
  const int m0 = wg << 7;

  // staging (rule #21: linear LDS dest + pre-swizzled source slot)
  const int ar = tid >> 2;
  const int as = (tid & 3) ^ ((ar >> 1) & 3);
  const u16* gA = A + (size_t)(m0 + ar) * 1024 + as * 8;
  const u16* gB = Bp + (size_t)ar * 1024 + as * 8;
  const size_t bstr = (size_t)128 * 1024;

#define STA(buf, kt) GLD(gA + (kt) * 32, &sA[buf][tid * 8])
#define STB(buf, kt, i) GLD(gB + bstr * (i) + (kt) * 32, &sB[buf][(i)*4096 + tid * 8])

  const int wm = (w >> 2) << 6;  // 0/64
  const int wi = w & 3;
  const int fr = l & 15, lh = l >> 4;
  const int swA = lh ^ (((wm + fr) >> 1) & 3);
  const int abase = ((wm + fr) << 5) + swA * 8;  // + mi*512
  const int swB = lh ^ ((fr >> 1) & 3);
  const int bbase = (wi << 10) + (fr << 5) + swB * 8;  // + j<<12 (+512 odd nj)

  f32x4 acc[4][8] = {};
  short8 Af[4], Bf0, Bf1;
  const int NT = 32;

#define LDAF(c)                                                                \
  _Pragma("unroll") for (int mi = 0; mi < 4; ++mi)                             \
      Af[mi] = *(const short8*)&sA[c][abase + mi * 512];
#define LDBF(c, j)                                                             \
  Bf0 = *(const short8*)&sB[c][((j) << 12) + bbase];                           \
  Bf1 = *(const short8*)&sB[c][((j) << 12) + bbase + 512];
#define MML(j)                                                                 \
  _Pragma("unroll") for (int mi = 0; mi < 4; ++mi) {                           \
    acc[mi][2 * (j)] = __builtin_amdgcn_mfma_f32_16x16x32_bf16(                \
        Af[mi], Bf0, acc[mi][2 * (j)], 0, 0, 0);                               \
    acc[mi][2 * (j) + 1] = __builtin_amdgcn_mfma_f32_16x16x32_bf16(            \
        Af[mi], Bf1, acc[mi][2 * (j) + 1], 0, 0, 0);                           \
  }

  // prologue: tile0 + tile1 fully staged
  STA(0, 0); STB(0, 0, 0); STB(0, 0, 1); STB(0, 0, 2); STB(0, 0, 3);
  STA(1, 1); STB(1, 1, 0); STB(1, 1, 1); STB(1, 1, 2); STB(1, 1, 3);
  asm volatile("s_waitcnt vmcnt(5)" ::: "memory");
  __builtin_amdgcn_s_barrier();

  for (int t = 0; t < NT; ++t) {
    const int c = t & 1;
    // P0: nj 0,1 ; stage A(t+1), Bq3(t+1)
    LDAF(c);
    LDBF(c, 0);
    if (t + 1 < NT) { STA(c ^ 1, t + 1); STB(c ^ 1, t + 1, 3); }
    BAR_LGKM();
    __builtin_amdgcn_s_setprio(1);
    MML(0);
    __builtin_amdgcn_s_setprio(0);
    TRAIL_BAR();
    // P1: nj 2,3 ; stage Bq0(t+2)
    LDBF(c, 1);
    if (t + 2 < NT) STB(c, t + 2, 0);
    BAR_LGKM();
    __builtin_amdgcn_s_setprio(1);
    MML(1);
    __builtin_amdgcn_s_setprio(0);
    TRAIL_BAR();
    // P2: nj 4,5 ; stage Bq1(t+2)
    LDBF(c, 2);
    if (t + 2 < NT) STB(c, t + 2, 1);
    BAR_LGKM();
    __builtin_amdgcn_s_setprio(1);
    MML(2);
    __builtin_amdgcn_s_setprio(0);
    TRAIL_BAR();
    // P3: nj 6,7 ; stage Bq2(t+2)
    LDBF(c, 3);
    if (t + 2 < NT) STB(c, t + 2, 2);
    BAR_LGKM();
    __builtin_amdgcn_s_setprio(1);
    MML(3);
    __builtin_amdgcn_s_setprio(0);
    __builtin_amdgcn_sched_barrier(0);
    if (t + 2 < NT) {
      asm volatile("s_waitcnt vmcnt(3)" ::: "memory");
    } else if (t + 1 < NT) {
      asm volatile("s_waitcnt vmcnt(0)" ::: "memory");
    }
    __builtin_amdgcn_s_barrier();
  }

  // ---- fused LayerNorm epilogue ----
  float bias[8], sc8[8], bi8[8];
#pragma unroll
  for (int nj = 0; nj < 8; ++nj) {
    int col = (wi << 7) + (nj << 4) + fr;
    bias[nj] = cr[col] - ci[col];
    sc8[nj] = lns[col];
    bi8[nj] = lnb[col];
  }
  float rsA[4][4], rqA[4][4];
#pragma unroll
  for (int mi = 0; mi < 4; ++mi) {
#pragma unroll
    for (int q = 0; q < 4; ++q) {
      float s = 0.f, ss = 0.f;
#pragma unroll
      for (int nj = 0; nj < 8; ++nj) {
        float v = acc[mi][nj][q] + bias[nj];
        acc[mi][nj][q] = v;
        s += v;
        ss += v * v;
      }
#pragma unroll
      for (int mk = 1; mk <= 8; mk <<= 1) {
        s += __shfl_xor(s, mk, 64);
        ss += __shfl_xor(ss, mk, 64);
      }
      rsA[mi][q] = s;
      rqA[mi][q] = ss;
      if (fr == 0) {
        int r = wm + mi * 16 + lh * 4 + q;
        lntab[r][wi][0] = s;
        lntab[r][wi][1] = ss;
      }
    }
  }
  __syncthreads();
#pragma unroll
  for (int mi = 0; mi < 4; ++mi) {
#pragma unroll
    for (int q = 0; q < 4; ++q) {
      int r = wm + mi * 16 + lh * 4 + q;
      float S = 0.f, Q = 0.f;
#pragma unroll
      for (int w2 = 0; w2 < 4; ++w2) {
        S += lntab[r][w2][0];
        Q += lntab[r][w2][1];
      }
      float mean = S * (1.f / 512.f);
      float var = Q * (1.f / 512.f) - mean * mean;
      float rstd = rsqrtf(var + 1e-6f);
#pragma unroll
      for (int nj = 0; nj < 8; ++nj) {
        int col = (wi << 7) + (nj << 4) + fr;
        float val = (acc[mi][nj][q] - mean) * rstd * sc8[nj] + bi8[nj];
        Out[(size_t)(m0 + r) * 512 + col] = f2bf(val);
      }
    }
  }
#undef STA
#undef STB
#undef LDAF
#undef LDBF
#undef MML
#undef BAR_LGKM
#undef TRAIL_BAR
}

// ---------------- scan: 64 chunks x 32 steps, 4 complex ch/thread ----------
// u layout interleaved: [m][1024] bf16, col 2h = re, 2h+1 = im.

__global__ __launch_bounds__(256) void scan_fin(const u16* __restrict__ u,
                                                const float* __restrict__ cst,
                                                float2* __restrict__ fin) {
  int g = blockIdx.x * 256 + threadIdx.x;  // 131072
  int q = g & 127, b = (g >> 7) & 15, c = g >> 11;  // c 0..63
  int h0 = q << 2;
  float lr[4], li[4], fr[4], fi[4];
#pragma unroll
  for (int k = 0; k < 4; ++k) {
    lr[k] = cst[h0 + k];
    li[k] = cst[512 + h0 + k];
    fr[k] = 0.f;
    fi[k] = 0.f;
  }
  const u16* p = u + (size_t)(b * 2048 + c * 32) * 1024 + (h0 << 1);
#pragma unroll 4
  for (int j = 0; j < 32; ++j) {
    ushort8 v = *(const ushort8*)p;
#pragma unroll
    for (int k = 0; k < 4; ++k) {
      float ur = bf2f(v[2 * k]), ui = bf2f(v[2 * k + 1]);
      float nr = fmaf(lr[k], fr[k], fmaf(-li[k], fi[k], ur));
      float ni = fmaf(lr[k], fi[k], fmaf(li[k], fr[k], ui));
      fr[k] = nr;
      fi[k] = ni;
    }
    p += 1024;
  }
  float2* fo = fin + (size_t)(c * 16 + b) * 512 + h0;
#pragma unroll
  for (int k = 0; k < 4; ++k) fo[k] = make_float2(fr[k], fi[k]);
}

__global__ __launch_bounds__(256) void scan_out(const u16* __restrict__ u,
                                                const float* __restrict__ cst,
                                                const float2* __restrict__ fin,
                                                u16* __restrict__ hcat) {
  int g = blockIdx.x * 256 + threadIdx.x;
  int q = g & 127, b = (g >> 7) & 15, c = g >> 11;
  int h0 = q << 2;
  float lr[4], li[4], Lr[4], Li[4], sr[4], si[4];
#pragma unroll
  for (int k = 0; k < 4; ++k) {
    lr[k] = cst[h0 + k];
    li[k] = cst[512 + h0 + k];
    Lr[k] = cst[1024 + h0 + k];  // lam^32
    Li[k] = cst[1536 + h0 + k];
    sr[k] = 0.f;
    si[k] = 0.f;
  }
  // carry = scan over previous chunk finals with lam^32
  for (int c2 = 0; c2 < c; ++c2) {
    const float2* f = fin + (size_t)(c2 * 16 + b) * 512 + h0;
#pragma unroll
    for (int k = 0; k < 4; ++k) {
      float2 fv = f[k];
      float nr = fmaf(Lr[k], sr[k], fmaf(-Li[k], si[k], fv.x));
      float ni = fmaf(Lr[k], si[k], fmaf(Li[k], sr[k], fv.y));
      sr[k] = nr;
      si[k] = ni;
    }
  }
  size_t mb = (size_t)(b * 2048 + c * 32) * 1024 + (h0 << 1);
  const u16* p = u + mb;
  u16* o = hcat + mb;
#pragma unroll 4
  for (int j = 0; j < 32; ++j) {
    ushort8 v = *(const ushort8*)p;
    ushort8 ov;
#pragma unroll
    for (int k = 0; k < 4; ++k) {
      float ur = bf2f(v[2 * k]), ui = bf2f(v[2 * k + 1]);
      float nr = fmaf(lr[k], sr[k], fmaf(-li[k], si[k], ur));
      float ni = fmaf(lr[k], si[k], fmaf(li[k], sr[k], ui));
      sr[k] = nr;
      si[k] = ni;
      ov[2 * k] = f2bf(nr);
      ov[2 * k + 1] = f2bf(ni);
    }
    *(ushort8*)o = ov;
    p += 1024;
    o += 1024;
  }
}

// ---------------- launch ----------------
extern "C" void kernel_launch(void* const* d_in, const int* in_sizes, int n_in,
                              void* d_out, int out_size, void* d_ws,
                              size_t ws_size, hipStream_t stream) {
  const float* x   = (const float*)d_in[0];
  const float* nu  = (const float*)d_in[1];
  const float* th  = (const float*)d_in[2];
  const float* gl  = (const float*)d_in[3];
  const float* Br  = (const float*)d_in[4];
  const float* br  = (const float*)d_in[5];
  const float* Bi  = (const float*)d_in[6];
  const float* bi  = (const float*)d_in[7];
  const float* Cr  = (const float*)d_in[8];
  const float* cr  = (const float*)d_in[9];
  const float* Ci  = (const float*)d_in[10];
  const float* ci  = (const float*)d_in[11];
  const float* lns = (const float*)d_in[12];
  const float* lnb = (const float*)d_in[13];
  const float* W1  = (const float*)d_in[14];
  const float* b1  = (const float*)d_in[15];
  const float* W2  = (const float*)d_in[16];
  const float* b2  = (const float*)d_in[17];

  char* ws = (char*)d_ws;
  size_t off = 0;
  auto alloc = [&](size_t bytes) {
    char* p = ws + off;
    off += (bytes + 255) & ~(size_t)255;
    return p;
  };
  float* cst  = (float*)alloc(2560 * 4);
  u16* BcT    = (u16*)alloc((size_t)1024 * 512 * 2);   // interleaved Br/Bi rows
  u16* WcT    = (u16*)alloc((size_t)512 * 1024 * 2);   // permB rows, interleaved cols
  u16* W1T    = (u16*)alloc((size_t)2048 * 512 * 2);
  u16* W2T    = (u16*)alloc((size_t)512 * 2048 * 2);
  float2* fin = (float2*)alloc((size_t)64 * 16 * 512 * 8);
  u16* xb     = (u16*)alloc((size_t)32768 * 512 * 2);   // x bf16; later ybn
  u16* big1   = (u16*)alloc((size_t)32768 * 1024 * 2);  // u ; later h1
  u16* big2   = (u16*)alloc((size_t)32768 * 1024 * 2);  // hcat
  (void)in_sizes; (void)n_in; (void)out_size; (void)ws_size;

  k_const<<<dim3(1), dim3(512), 0, stream>>>(nu, th, gl, cst);
  prep_all<<<dim3(3072), dim3(256), 0, stream>>>(Br, Bi, Cr, Ci, W1, W2, BcT,
                                                 WcT, W1T, W2T);
  cast_bf<<<dim3(8192), dim3(256), 0, stream>>>(x, xb);

  // G1: u = gamma*(x@[Br|Bi] + bias) -> bf16 interleaved big1 [32768][1024]
  gemm8p<0><<<dim3(512), dim3(512), 0, stream>>>(
      xb, BcT, (void*)big1, 32768, 1024, 512, cst + 2048, br, bi);
  // scan
  scan_fin<<<dim3(512), dim3(256), 0, stream>>>(big1, cst, fin);
  scan_out<<<dim3(512), dim3(256), 0, stream>>>(big1, cst, fin, big2);
  // G2 + LN fused -> ybn bf16 into xb
  gemm_ln<<<dim3(256), dim3(512), 0, stream>>>(big2, WcT, xb, cr, ci, lns, lnb);
  // G3: h1 = ybn@W1 + b1 -> bf16 big1
  gemm8p<2><<<dim3(1024), dim3(512), 0, stream>>>(
      xb, W1T, (void*)big1, 32768, 2048, 512, b1, nullptr, nullptr);
  // G4: out = h1@W2 + b2 -> f32 d_out
  gemm8p<3><<<dim3(256), dim3(512), 0, stream>>>(
      big1, W2T, d_out, 32768, 512, 2048, b2, nullptr, nullptr);
}